// Round 5
// baseline (299.331 us; speedup 1.0000x reference)
//
#include <hip/hip_runtime.h>
#include <math.h>

#define B_SZ   1024
#define CDIM   768
#define POOL   100
#define COSEPS 1e-6f
#define NTHR   256
#define BATCH  2048   // float4s per batch = 8 * NTHR (32 KB)

typedef __attribute__((ext_vector_type(4))) float f32x4;

// Batched copy: each batch = 2048 float4s; 8 nt-loads then 8 stores per thread.
__device__ __forceinline__ void copy_batches(const f32x4* __restrict__ src,
                                             f32x4* __restrict__ dst,
                                             int b0, int b1, int cid, int nblk, int t) {
    for (int bt = b0 + cid; bt < b1; bt += nblk) {
        const f32x4* s = src + (size_t)bt * BATCH + t;
        f32x4*       d = dst + (size_t)bt * BATCH + t;
        f32x4 v0 = __builtin_nontemporal_load(s);
        f32x4 v1 = __builtin_nontemporal_load(s + 1 * NTHR);
        f32x4 v2 = __builtin_nontemporal_load(s + 2 * NTHR);
        f32x4 v3 = __builtin_nontemporal_load(s + 3 * NTHR);
        f32x4 v4 = __builtin_nontemporal_load(s + 4 * NTHR);
        f32x4 v5 = __builtin_nontemporal_load(s + 5 * NTHR);
        f32x4 v6 = __builtin_nontemporal_load(s + 6 * NTHR);
        f32x4 v7 = __builtin_nontemporal_load(s + 7 * NTHR);
        d[0 * NTHR] = v0;  d[1 * NTHR] = v1;  d[2 * NTHR] = v2;  d[3 * NTHR] = v3;
        d[4 * NTHR] = v4;  d[5 * NTHR] = v5;  d[6 * NTHR] = v6;  d[7 * NTHR] = v7;
    }
}

// ---------------- K1: prep (blocks 0..99) + copy batches [0,nb1) ------------
__global__ __launch_bounds__(NTHR)
void k1_prep_copy(const float* __restrict__ A, const float* __restrict__ K,
                  float* __restrict__ W1, float* __restrict__ W2,
                  float* __restrict__ knorm,
                  const f32x4* __restrict__ src4, f32x4* __restrict__ dst4,
                  int nb1) {
    const int blk = blockIdx.x, t = threadIdx.x;
    if (blk >= POOL) {
        copy_batches(src4, dst4, 0, nb1, blk - POOL, gridDim.x - POOL, t);
        return;
    }
    __shared__ float red[NTHR];
    const int k = blk;
    const float* Ar = A + (size_t)k * CDIM;
    const float* Kr = K + (size_t)k * CDIM;

    float m = -INFINITY;
    for (int d = t; d < CDIM; d += NTHR) m = fmaxf(m, Ar[d]);
    red[t] = m; __syncthreads();
    for (int s = 128; s > 0; s >>= 1) { if (t < s) red[t] = fmaxf(red[t], red[t + s]); __syncthreads(); }
    m = red[0]; __syncthreads();

    float sum = 0.f;
    for (int d = t; d < CDIM; d += NTHR) sum += expf(Ar[d] - m);
    red[t] = sum; __syncthreads();
    for (int s = 128; s > 0; s >>= 1) { if (t < s) red[t] += red[t + s]; __syncthreads(); }
    sum = red[0]; __syncthreads();
    const float inv = 1.0f / sum;

    float ksq = 0.f;
    for (int d = t; d < CDIM; d += NTHR) { float kv = Kr[d]; ksq += kv * kv; }
    red[t] = ksq; __syncthreads();
    for (int s = 128; s > 0; s >>= 1) { if (t < s) red[t] += red[t + s]; __syncthreads(); }
    if (t == 0) knorm[k] = fmaxf(sqrtf(red[0]), COSEPS);

    for (int d = t; d < CDIM; d += NTHR) {
        float a_sm = expf(Ar[d] - m) * inv;
        W1[(size_t)k * CDIM + d] = a_sm * Kr[d];
        W2[(size_t)k * CDIM + d] = a_sm * a_sm;
    }
}

// ---------------- K2: aq (1024 blocks) + copy batches [nb1,nb2) -------------
__global__ __launch_bounds__(NTHR)
void k2_aq_copy(const float* __restrict__ xq,
                const float* __restrict__ W1, const float* __restrict__ W2,
                const float* __restrict__ knorm, float* __restrict__ aq,
                const f32x4* __restrict__ src4, f32x4* __restrict__ dst4,
                int nb1, int nb2) {
    const int blk = blockIdx.x, t = threadIdx.x;
    const int role = (blk >> 3) & 1;                // both roles on every XCD
    const int id   = ((blk >> 4) << 3) | (blk & 7); // 0..1023 per role

    if (role) {
        copy_batches(src4, dst4, nb1, nb2, id, 1024, t);
        return;
    }

    __shared__ float xs[CDIM];
    __shared__ float x2s[CDIM];
    const int b = id;
    for (int d = t; d < CDIM; d += NTHR) {
        float v = xq[(size_t)b * CDIM + d];
        xs[d] = v; x2s[d] = v * v;
    }
    __syncthreads();

    const int wave = t >> 6, lane = t & 63;
    for (int k = wave; k < POOL; k += 4) {
        const float* w1 = W1 + (size_t)k * CDIM;
        const float* w2 = W2 + (size_t)k * CDIM;
        float s1 = 0.f, s2 = 0.f;
        #pragma unroll
        for (int i = 0; i < CDIM / 64; ++i) {
            int d = lane + i * 64;
            s1 += xs[d]  * w1[d];
            s2 += x2s[d] * w2[d];
        }
        for (int off = 32; off > 0; off >>= 1) {
            s1 += __shfl_down(s1, off);
            s2 += __shfl_down(s2, off);
        }
        if (lane == 0) {
            float an = fmaxf(sqrtf(s2), COSEPS);
            float v  = s1 / (an * knorm[k]);
            aq[(size_t)b * POOL + k] = (v + 1.0f) * 0.5f;
        }
    }
}

// ---------------- K3: p-contraction (1024 blocks) + copy [nb2,NB) + tail ----
__global__ __launch_bounds__(NTHR)
void k3_p_copy(const float* __restrict__ aq, const float* __restrict__ p,
               float* __restrict__ out,
               const f32x4* __restrict__ src4, f32x4* __restrict__ dst4,
               int nb2, int NB, int n4) {
    const int blk = blockIdx.x, t = threadIdx.x;
    const int role = (blk >> 3) & 1;
    const int id   = ((blk >> 4) << 3) | (blk & 7);

    if (role) {
        copy_batches(src4, dst4, nb2, NB, id, 1024, t);
        // tail: n4 % BATCH float4s (0 for the actual shapes, guarded anyway)
        for (int i = NB * BATCH + id * NTHR + t; i < n4; i += 1024 * NTHR)
            dst4[i] = src4[i];
        return;
    }

    __shared__ float a_s[POOL * 8];
    const int l  = id & 7;
    const int bg = id >> 3;

    for (int i = t; i < POOL * 8; i += NTHR) {
        int bb = i & 7, k = i >> 3;
        a_s[i] = aq[(size_t)(bg * 8 + bb) * POOL + k];
    }
    __syncthreads();

    const float* pl = p + (size_t)l * POOL * CDIM + t;
    float acc[8][3];
    #pragma unroll
    for (int bb = 0; bb < 8; ++bb)
        #pragma unroll
        for (int j = 0; j < 3; ++j) acc[bb][j] = 0.f;

    for (int k = 0; k < POOL; ++k) {
        float p0 = pl[(size_t)k * CDIM];
        float p1 = pl[(size_t)k * CDIM + 256];
        float p2 = pl[(size_t)k * CDIM + 512];
        #pragma unroll
        for (int bb = 0; bb < 8; ++bb) {
            float a = a_s[k * 8 + bb];
            acc[bb][0] += a * p0;
            acc[bb][1] += a * p1;
            acc[bb][2] += a * p2;
        }
    }

    const size_t EK_SZ = (size_t)B_SZ * 4 * CDIM;
    #pragma unroll
    for (int bb = 0; bb < 8; ++bb) {
        int b = bg * 8 + bb;
        float* dst = (l < 4)
            ? out + (size_t)b * (4 * CDIM) + (size_t)l * CDIM
            : out + EK_SZ + (size_t)b * (4 * CDIM) + (size_t)(l - 4) * CDIM;
        dst[t]       = acc[bb][0];
        dst[t + 256] = acc[bb][1];
        dst[t + 512] = acc[bb][2];
    }
}

extern "C" void kernel_launch(void* const* d_in, const int* in_sizes, int n_in,
                              void* d_out, int out_size, void* d_ws, size_t ws_size,
                              hipStream_t stream) {
    const float* x_querry = (const float*)d_in[0];
    const float* x_block  = (const float*)d_in[1];
    const float* K        = (const float*)d_in[2];
    const float* A        = (const float*)d_in[3];
    const float* p        = (const float*)d_in[4];
    float* out = (float*)d_out;

    // workspace layout (floats)
    float* W1    = (float*)d_ws;                 // 100*768
    float* W2    = W1 + POOL * CDIM;             // 100*768
    float* knorm = W2 + POOL * CDIM;             // 100 (pad 128)
    float* aq    = knorm + 128;                  // 1024*100

    const size_t EK_SZ = (size_t)B_SZ * 4 * CDIM;
    const f32x4* src4 = (const f32x4*)x_block;
    f32x4* dst4 = (f32x4*)(out + 2 * EK_SZ);

    const int n4 = in_sizes[1] / 4;              // 38,731,776
    const int NB = n4 / BATCH;                   // 18,912 full batches
    // K2/K3 copy shares: multiples of 1024 batches (no per-block tail imbalance)
    int per23 = (int)(NB * 0.16) / 1024 * 1024;  // -> 3072 for NB=18912
    if (per23 < 0) per23 = 0;
    int nb1 = NB - 2 * per23;                    // K1 share (~67.5%)
    if (nb1 < 0) nb1 = 0;
    const int nb2 = nb1 + per23;

    k1_prep_copy<<<2048, NTHR, 0, stream>>>(A, K, W1, W2, knorm, src4, dst4, nb1);
    k2_aq_copy  <<<2048, NTHR, 0, stream>>>(x_querry, W1, W2, knorm, aq, src4, dst4, nb1, nb2);
    k3_p_copy   <<<2048, NTHR, 0, stream>>>(aq, p, out, src4, dst4, nb2, NB, n4);
}